// Round 1
// 497.072 us; speedup vs baseline: 1.0652x; 1.0652x over previous
//
#include <hip/hip_runtime.h>
#include <math.h>

// Problem constants
#define B_     16
#define T_     60
#define N_     196
#define C_     512
#define SEGS_  10
#define TOPK_  6
#define TOPM_  12
#define HEADS_ 4
#define HD_    128
#define CLIP_  6
#define FRAMES_ 36

// workspace layout (float indices)
#define WS_Q    0      // 512 floats: q for batch 0 (incl. bq)
#define WS_SCP  512    // 8*196 floats: partial scores [head*2+half][n], pre-scaled
#define WS_PID  2080   // 1 int: pid

#define SCALE_ 0.08838834764831845f  // 1/sqrt(128)

// ---------------------------------------------------------------------------
// Phase 1: q = qst_feat[0] @ Wq^T + bq  (512 dot-512), 64 blocks x 8 rows.
// Each half-wave (32 lanes) owns one output row; butterfly reduce.
// ---------------------------------------------------------------------------
__global__ void qproj_kernel(const float* __restrict__ qst,
                             const float* __restrict__ ipw,
                             const float* __restrict__ ipb,
                             float* __restrict__ ws) {
    __shared__ float x[C_];
    int tid = threadIdx.x;  // 256 threads
    x[tid]       = qst[tid];
    x[tid + 256] = qst[tid + 256];
    __syncthreads();

    int wave = tid >> 6, lane = tid & 63;
    int half = lane >> 5, l = lane & 31;
    int row = blockIdx.x * 8 + wave * 2 + half;   // 64 blocks * 8 = 512 rows

    const float4* w4 = (const float4*)(ipw + (size_t)row * C_);
    const float4* x4 = (const float4*)x;
    float acc = 0.f;
    #pragma unroll
    for (int j = 0; j < 4; ++j) {
        float4 wv = w4[l + 32 * j];
        float4 xv = x4[l + 32 * j];
        acc += wv.x * xv.x + wv.y * xv.y + wv.z * xv.z + wv.w * xv.w;
    }
    // reduce within each 32-lane half (xor offsets <32 never cross the half)
    for (int off = 16; off; off >>= 1) acc += __shfl_xor(acc, off);
    if (l == 0) ws[WS_Q + row] = acc + ipb[row];
}

// ---------------------------------------------------------------------------
// Phase 2: bilinear reformulation.
//   u_h[c]       = sum_d q[h*128+d] * Wk[h*128+d, c]     (fold q into Wk)
//   score[h][n]  = sum_c u_h[c] * x_n[c]   (+ const per head -> dropped,
//                                            cancels in softmax)
// 8 blocks: h = blk>>1, c-half = blk&1 (256 columns each). Each block writes
// PARTIAL scores (its c-half contribution) to its own ws slot — no atomics.
// ---------------------------------------------------------------------------
__global__ void score_kernel(const float* __restrict__ patch,
                             const int* __restrict__ tk,
                             const float* __restrict__ ipw,
                             float* __restrict__ ws) {
    __shared__ float qh[HD_];
    __shared__ float us[256];
    int tid = threadIdx.x;                 // 256 threads
    int h = blockIdx.x >> 1, half = blockIdx.x & 1;
    int c = half * 256 + tid;

    if (tid < HD_) qh[tid] = ws[WS_Q + h * HD_ + tid];
    __syncthreads();

    // u for this block's 256-column slice: column walk of Wk, coalesced
    const float* wk = ipw + (size_t)(C_ + h * HD_) * C_ + c;
    float u = 0.f;
    #pragma unroll 16
    for (int d = 0; d < HD_; ++d) u += qh[d] * wk[(size_t)d * C_];
    us[tid] = u;
    __syncthreads();

    // partial scores: wave w handles n = w, w+4, ...  (49 per wave)
    int fid0 = tk[0] * CLIP_;              // b=0, k=0, c=0
    const float* pb = patch + (size_t)fid0 * N_ * C_ + half * 256;
    int wave = tid >> 6, lane = tid & 63;
    const float4* u4 = (const float4*)us;
    float4 uv = u4[lane];
    for (int n = wave; n < N_; n += 4) {
        const float4* x4 = (const float4*)(pb + (size_t)n * C_);
        float4 xv = x4[lane];              // 64 lanes x 16B = 1KB coalesced
        float p = uv.x * xv.x + uv.y * xv.y + uv.z * xv.z + uv.w * xv.w;
        for (int off = 32; off; off >>= 1) p += __shfl_down(p, off);
        if (lane == 0)
            ws[WS_SCP + (size_t)blockIdx.x * N_ + n] = p * SCALE_;
    }
}

// ---------------------------------------------------------------------------
// Phase 3: sum partials, softmax per head over n, mean over heads, top-12
// -> pid. (logic identical to previously-verified version)
// ---------------------------------------------------------------------------
__global__ void pid_kernel(float* __restrict__ ws) {
    __shared__ float wgt[HEADS_][N_];
    __shared__ float pw[N_];
    int tid = threadIdx.x;  // 256
    int h = tid >> 6, j = tid & 63;

    // wave h handles head h: lanes own n = j + 64*s
    float sc[4]; float ex[4];
    int m = 0;
    float mx = -1e30f;
    for (int n = j; n < N_; n += 64) {
        sc[m] = ws[WS_SCP + (size_t)(2 * h) * N_ + n]
              + ws[WS_SCP + (size_t)(2 * h + 1) * N_ + n];
        mx = fmaxf(mx, sc[m]);
        ++m;
    }
    for (int off = 1; off < 64; off <<= 1) mx = fmaxf(mx, __shfl_xor(mx, off));
    float sum = 0.f;
    for (int s = 0; s < m; ++s) { ex[s] = expf(sc[s] - mx); sum += ex[s]; }
    for (int off = 1; off < 64; off <<= 1) sum += __shfl_xor(sum, off);
    float inv = 1.f / sum;
    m = 0;
    for (int n = j; n < N_; n += 64) { wgt[h][n] = ex[m] * inv; ++m; }
    __syncthreads();

    for (int n = tid; n < N_; n += 256)
        pw[n] = 0.25f * (wgt[0][n] + wgt[1][n] + wgt[2][n] + wgt[3][n]);
    __syncthreads();

    // wave 0: 12 rounds of parallel argmax; ties prefer larger index
    // (stable ascending argsort + take-last => larger index wins at boundary)
    if (tid < 64) {
        float v[4];
        for (int s = 0; s < 4; ++s) {
            int n = j + 64 * s;
            v[s] = (n < N_) ? pw[n] : -1e30f;
        }
        int pid = -1;
        for (int r = 0; r < TOPM_; ++r) {
            float bv = -1e30f; int bi = -1;
            for (int s = 0; s < 4; ++s) {
                int n = j + 64 * s;
                if (v[s] > bv || (v[s] == bv && n > bi)) { bv = v[s]; bi = n; }
            }
            for (int off = 1; off < 64; off <<= 1) {
                float ov = __shfl_xor(bv, off);
                int   oi = __shfl_xor(bi, off);
                if (ov > bv || (ov == bv && oi > bi)) { bv = ov; bi = oi; }
            }
            if ((bi & 63) == j) v[bi >> 6] = -1e30f;
            if (bi > pid) pid = bi;
        }
        if (j == 0) ((int*)ws)[WS_PID] = pid;
    }
}

// ---------------------------------------------------------------------------
// Phase 4: gather outputs.
// out0 = audio_feat[b, fid, :]                         (B,F,C)
// out1 = patch_feat[b, fid, pid, :] bcast x12          (B,F,12,C)
// out2 = same reshaped                                 (B,F*12,C)
// ---------------------------------------------------------------------------
__global__ void out_kernel(const float* __restrict__ audio,
                           const float* __restrict__ patch,
                           const int* __restrict__ tk,
                           const float* __restrict__ ws,
                           float* __restrict__ out) {
    int bf = blockIdx.x;               // 0 .. B*FRAMES-1
    int b = bf / FRAMES_, f = bf % FRAMES_;
    int k = f / CLIP_, c = f % CLIP_;
    int fid = tk[b * TOPK_ + k] * CLIP_ + c;
    int t = threadIdx.x;               // 0..127, float4 lanes over C
    int pid = ((const int*)ws)[WS_PID];

    const float4* a4 = (const float4*)(audio + ((size_t)b * T_ + fid) * C_);
    const float4* p4 = (const float4*)(patch + (((size_t)b * T_ + fid) * N_ + pid) * C_);
    float4 av = a4[t];
    float4 sv = p4[t];

    float4* o0 = (float4*)out;
    float4* o1 = (float4*)(out + (size_t)B_ * FRAMES_ * C_);
    float4* o2 = (float4*)(out + (size_t)B_ * FRAMES_ * C_ + (size_t)B_ * FRAMES_ * TOPM_ * C_);

    o0[(size_t)bf * (C_ / 4) + t] = av;
    size_t rb = (size_t)bf * TOPM_ * (C_ / 4);
    #pragma unroll
    for (int mm = 0; mm < TOPM_; ++mm) {
        o1[rb + mm * (C_ / 4) + t] = sv;
        o2[rb + mm * (C_ / 4) + t] = sv;
    }
}

extern "C" void kernel_launch(void* const* d_in, const int* in_sizes, int n_in,
                              void* d_out, int out_size, void* d_ws, size_t ws_size,
                              hipStream_t stream) {
    const float* audio = (const float*)d_in[0];   // (B,T,C)
    const float* patch = (const float*)d_in[1];   // (B,T,N,C)
    const float* qst   = (const float*)d_in[2];   // (B,C)
    const int*   tk    = (const int*)d_in[3];     // (B,1,TOP_K)
    const float* ipw   = (const float*)d_in[4];   // (3C,C)
    const float* ipb   = (const float*)d_in[5];   // (3C,)
    // d_in[6..13] (out_w/out_b/lin1/lin2/ln) are dead w.r.t. the returned outputs
    float* out = (float*)d_out;
    float* ws  = (float*)d_ws;

    qproj_kernel<<<64, 256, 0, stream>>>(qst, ipw, ipb, ws);
    score_kernel<<<8, 256, 0, stream>>>(patch, tk, ipw, ws);
    pid_kernel<<<1, 256, 0, stream>>>(ws);
    out_kernel<<<B_ * FRAMES_, 128, 0, stream>>>(audio, patch, tk, ws, out);
}

// Round 2
// 474.756 us; speedup vs baseline: 1.1152x; 1.0470x over previous
//
#include <hip/hip_runtime.h>
#include <math.h>

// Problem constants
#define B_     16
#define T_     60
#define N_     196
#define C_     512
#define SEGS_  10
#define TOPK_  6
#define TOPM_  12
#define HEADS_ 4
#define HD_    128
#define CLIP_  6
#define FRAMES_ 36

// workspace layout (float indices)
#define WS_Q    0      // 512 floats: q for batch 0 (incl. bq)
#define WS_SCP  512    // 16*196 floats: partial scores [head*4+quarter][n], pre-scaled
#define WS_PID  3648   // (unused slot, kept for layout clarity)

#define SCALE_ 0.08838834764831845f  // 1/sqrt(128)

// ---------------------------------------------------------------------------
// Phase 1: q = qst_feat[0] @ Wq^T + bq  (512 dot-512), 64 blocks x 8 rows.
// Each half-wave (32 lanes) owns one output row; butterfly reduce.
// ---------------------------------------------------------------------------
__global__ void qproj_kernel(const float* __restrict__ qst,
                             const float* __restrict__ ipw,
                             const float* __restrict__ ipb,
                             float* __restrict__ ws) {
    __shared__ float x[C_];
    int tid = threadIdx.x;  // 256 threads
    x[tid]       = qst[tid];
    x[tid + 256] = qst[tid + 256];
    __syncthreads();

    int wave = tid >> 6, lane = tid & 63;
    int half = lane >> 5, l = lane & 31;
    int row = blockIdx.x * 8 + wave * 2 + half;   // 64 blocks * 8 = 512 rows

    const float4* w4 = (const float4*)(ipw + (size_t)row * C_);
    const float4* x4 = (const float4*)x;
    float acc = 0.f;
    #pragma unroll
    for (int j = 0; j < 4; ++j) {
        float4 wv = w4[l + 32 * j];
        float4 xv = x4[l + 32 * j];
        acc += wv.x * xv.x + wv.y * xv.y + wv.z * xv.z + wv.w * xv.w;
    }
    // reduce within each 32-lane half (xor offsets <32 never cross the half)
    for (int off = 16; off; off >>= 1) acc += __shfl_xor(acc, off);
    if (l == 0) ws[WS_Q + row] = acc + ipb[row];
}

// ---------------------------------------------------------------------------
// Phase 2: bilinear reformulation, 16 blocks = head x c-quarter (128 cols).
//   u_h[c]          = sum_d q[h*128+d] * Wk[h*128+d, c]
//   part[h*4+qt][n] = sum_{c in quarter} u_h[c] * x_n[c]   (k-bias dropped:
//                      per-head constant, cancels in softmax)
// Each block writes PARTIAL scores for its quarter — no atomics.
// ---------------------------------------------------------------------------
__global__ void score_kernel(const float* __restrict__ patch,
                             const int* __restrict__ tk,
                             const float* __restrict__ ipw,
                             float* __restrict__ ws) {
    __shared__ float qh[HD_];
    __shared__ float upart[2][128];
    __shared__ float us[128];
    int tid = threadIdx.x;                 // 256 threads
    int h = blockIdx.x >> 2, qt = blockIdx.x & 3;

    if (tid < HD_) qh[tid] = ws[WS_Q + h * HD_ + tid];
    __syncthreads();

    // u for this block's 128-column slice: column walk of Wk, coalesced.
    // thread (dh, c): partial over 64 of the 128 d's.
    int c = tid & 127;
    int dh = tid >> 7;                     // 0..1
    const float* wk = ipw + (size_t)(C_ + h * HD_ + dh * 64) * C_ + qt * 128 + c;
    float u = 0.f;
    #pragma unroll 16
    for (int d = 0; d < 64; ++d) u += qh[dh * 64 + d] * wk[(size_t)d * C_];
    upart[dh][c] = u;
    __syncthreads();
    if (tid < 128) us[tid] = upart[0][tid] + upart[1][tid];
    __syncthreads();

    // partial scores: each 32-lane group owns one n per iteration.
    int fid0 = tk[0] * CLIP_;              // b=0, k=0, c=0
    const float* pb = patch + (size_t)fid0 * N_ * C_ + qt * 128;
    int wave = tid >> 6, lane = tid & 63;
    int g = lane >> 5, l = lane & 31;      // 2 n-groups of 32 lanes per wave
    const float4* u4 = (const float4*)us;
    float4 uv = u4[l];                     // 32 lanes x float4 = 128 cols
    for (int n = wave * 2 + g; n < N_; n += 8) {
        const float4* x4 = (const float4*)(pb + (size_t)n * C_);
        float4 xv = x4[l];
        float p = uv.x * xv.x + uv.y * xv.y + uv.z * xv.z + uv.w * xv.w;
        // xor offsets <32 stay within each 32-lane group
        for (int off = 16; off; off >>= 1) p += __shfl_xor(p, off);
        if (l == 0)
            ws[WS_SCP + (size_t)blockIdx.x * N_ + n] = p * SCALE_;
    }
}

// ---------------------------------------------------------------------------
// Phase 3+4 fused: every block recomputes pid (pure function of the 16
// partial-score rows — deterministic, no atomics), then gathers outputs.
// out0 = audio_feat[b, fid, :]                         (B,F,C)
// out1 = patch_feat[b, fid, pid, :] bcast x12          (B,F,12,C)
// out2 = same reshaped                                 (B,F*12,C)
// 576 blocks x 256 threads; the 12 copies split 6/6 across thread-halves.
// ---------------------------------------------------------------------------
__global__ void out_kernel(const float* __restrict__ audio,
                           const float* __restrict__ patch,
                           const int* __restrict__ tk,
                           const float* __restrict__ ws,
                           float* __restrict__ out) {
    __shared__ float wgt[HEADS_][N_];
    __shared__ float pw[N_];
    __shared__ int pid_s;
    int tid = threadIdx.x;  // 256
    int h = tid >> 6, j = tid & 63;

    // ---- pid recompute (identical logic to previously-verified pid_kernel)
    // wave h handles head h: lanes own n = j + 64*s
    float sc[4]; float ex[4];
    int m = 0;
    float mx = -1e30f;
    for (int n = j; n < N_; n += 64) {
        float s = ws[WS_SCP + (size_t)(h * 4 + 0) * N_ + n]
                + ws[WS_SCP + (size_t)(h * 4 + 1) * N_ + n]
                + ws[WS_SCP + (size_t)(h * 4 + 2) * N_ + n]
                + ws[WS_SCP + (size_t)(h * 4 + 3) * N_ + n];
        sc[m] = s;
        mx = fmaxf(mx, s);
        ++m;
    }
    for (int off = 1; off < 64; off <<= 1) mx = fmaxf(mx, __shfl_xor(mx, off));
    float sum = 0.f;
    for (int s = 0; s < m; ++s) { ex[s] = expf(sc[s] - mx); sum += ex[s]; }
    for (int off = 1; off < 64; off <<= 1) sum += __shfl_xor(sum, off);
    float inv = 1.f / sum;
    m = 0;
    for (int n = j; n < N_; n += 64) { wgt[h][n] = ex[m] * inv; ++m; }
    __syncthreads();

    for (int n = tid; n < N_; n += 256)
        pw[n] = 0.25f * (wgt[0][n] + wgt[1][n] + wgt[2][n] + wgt[3][n]);
    __syncthreads();

    // wave 0: 12 rounds of parallel argmax; ties prefer larger index
    // (stable ascending argsort + take-last => larger index wins at boundary)
    if (tid < 64) {
        float v[4];
        for (int s = 0; s < 4; ++s) {
            int n = j + 64 * s;
            v[s] = (n < N_) ? pw[n] : -1e30f;
        }
        int pid = -1;
        for (int r = 0; r < TOPM_; ++r) {
            float bv = -1e30f; int bi = -1;
            for (int s = 0; s < 4; ++s) {
                int n = j + 64 * s;
                if (v[s] > bv || (v[s] == bv && n > bi)) { bv = v[s]; bi = n; }
            }
            for (int off = 1; off < 64; off <<= 1) {
                float ov = __shfl_xor(bv, off);
                int   oi = __shfl_xor(bi, off);
                if (ov > bv || (ov == bv && oi > bi)) { bv = ov; bi = oi; }
            }
            if ((bi & 63) == j) v[bi >> 6] = -1e30f;
            if (bi > pid) pid = bi;
        }
        if (tid == 0) pid_s = pid;
    }
    __syncthreads();
    int pid = pid_s;

    // ---- gather/broadcast writes
    int bf = blockIdx.x;               // 0 .. B*FRAMES-1
    int b = bf / FRAMES_, f = bf % FRAMES_;
    int k = f / CLIP_, c = f % CLIP_;
    int fid = tk[b * TOPK_ + k] * CLIP_ + c;
    int t = tid & 127;                 // float4 lane over C
    int half = tid >> 7;               // which 6 of the 12 copies

    const float4* p4 = (const float4*)(patch + (((size_t)b * T_ + fid) * N_ + pid) * C_);
    float4 sv = p4[t];

    float4* o0 = (float4*)out;
    float4* o1 = (float4*)(out + (size_t)B_ * FRAMES_ * C_);
    float4* o2 = (float4*)(out + (size_t)B_ * FRAMES_ * C_ + (size_t)B_ * FRAMES_ * TOPM_ * C_);

    if (half == 0) {
        const float4* a4 = (const float4*)(audio + ((size_t)b * T_ + fid) * C_);
        o0[(size_t)bf * (C_ / 4) + t] = a4[t];
    }
    size_t rb = (size_t)bf * TOPM_ * (C_ / 4);
    #pragma unroll
    for (int mm = 0; mm < 6; ++mm) {
        int m2 = half * 6 + mm;
        o1[rb + m2 * (C_ / 4) + t] = sv;
        o2[rb + m2 * (C_ / 4) + t] = sv;
    }
}

extern "C" void kernel_launch(void* const* d_in, const int* in_sizes, int n_in,
                              void* d_out, int out_size, void* d_ws, size_t ws_size,
                              hipStream_t stream) {
    const float* audio = (const float*)d_in[0];   // (B,T,C)
    const float* patch = (const float*)d_in[1];   // (B,T,N,C)
    const float* qst   = (const float*)d_in[2];   // (B,C)
    const int*   tk    = (const int*)d_in[3];     // (B,1,TOP_K)
    const float* ipw   = (const float*)d_in[4];   // (3C,C)
    const float* ipb   = (const float*)d_in[5];   // (3C,)
    // d_in[6..13] (out_w/out_b/lin1/lin2/ln) are dead w.r.t. the returned outputs
    float* out = (float*)d_out;
    float* ws  = (float*)d_ws;

    qproj_kernel<<<64, 256, 0, stream>>>(qst, ipw, ipb, ws);
    score_kernel<<<16, 256, 0, stream>>>(patch, tk, ipw, ws);
    out_kernel<<<B_ * FRAMES_, 256, 0, stream>>>(audio, patch, tk, ws, out);
}